// Round 2
// baseline (428.848 us; speedup 1.0000x reference)
//
#include <hip/hip_runtime.h>

#define BN_EPS 1e-3f

// ---------------- K1: sparse GIN aggregation ----------------
// h0[b,i,f] = (1+eps)*x[b,i,f] + sum_{j: a[b,i,j]!=0} x[b,j,f]
// One block per output row (b,i); 128 threads = feature columns.
__global__ __launch_bounds__(128) void agg_kernel(
    const float* __restrict__ x, const float* __restrict__ a,
    const float* __restrict__ epsp, float* __restrict__ h0) {
    const int row = blockIdx.x;            // b*1024 + i
    const int b   = row >> 10;
    const int t   = threadIdx.x;           // 0..127

    __shared__ int idx[1024];
    __shared__ int cnt;
    if (t == 0) cnt = 0;
    __syncthreads();

    // scan adjacency row: two fully-coalesced float4 loads (2 KB each)
    const float4* arow = reinterpret_cast<const float4*>(a + (size_t)row * 1024);
    float4 v0 = arow[t];          // j = 4t .. 4t+3
    float4 v1 = arow[t + 128];    // j = 512 + 4t .. 512 + 4t+3
    const int j0 = t * 4;
    if (v0.x != 0.f) idx[atomicAdd(&cnt, 1)] = j0 + 0;
    if (v0.y != 0.f) idx[atomicAdd(&cnt, 1)] = j0 + 1;
    if (v0.z != 0.f) idx[atomicAdd(&cnt, 1)] = j0 + 2;
    if (v0.w != 0.f) idx[atomicAdd(&cnt, 1)] = j0 + 3;
    if (v1.x != 0.f) idx[atomicAdd(&cnt, 1)] = 512 + j0 + 0;
    if (v1.y != 0.f) idx[atomicAdd(&cnt, 1)] = 512 + j0 + 1;
    if (v1.z != 0.f) idx[atomicAdd(&cnt, 1)] = 512 + j0 + 2;
    if (v1.w != 0.f) idx[atomicAdd(&cnt, 1)] = 512 + j0 + 3;
    __syncthreads();

    const int n = cnt;
    const float* xb = x + (size_t)b * (1024 * 128);
    float acc = (1.0f + epsp[0]) * xb[(size_t)(row & 1023) * 128 + t];
    for (int q = 0; q < n; ++q) {
        acc += xb[(size_t)idx[q] * 128 + t];   // idx[q] uniform -> LDS broadcast
    }
    h0[(size_t)row * 128 + t] = acc;
}

// ---------------- K2: fused Dense+BN+ReLU GEMM ----------------
// out[M,256] = relu( ((A@W + bias) - m) * g/sqrt(v+eps) + be )
// 64x64 tile per block, 256 threads, 4x4 per thread, K-chunks of 16.
template <int K>
__global__ __launch_bounds__(256) void mlp_kernel(
    const float* __restrict__ A,    // [M][K]
    const float* __restrict__ W,    // [K][256]
    const float* __restrict__ bias, const float* __restrict__ g,
    const float* __restrict__ be,   const float* __restrict__ m,
    const float* __restrict__ v,    float* __restrict__ out) {
    __shared__ float At[16][64];    // [k][row]  (A-tile transposed)
    __shared__ float Wt[16][64];    // [k][col]

    const int tid   = threadIdx.x;
    const int mtile = blockIdx.x >> 2;      // 256/64 = 4 col tiles
    const int ntile = blockIdx.x & 3;
    const int row0  = mtile * 64;
    const int col0  = ntile * 64;
    const int tc = tid & 15;                // col group (x4)
    const int tr = tid >> 4;                // row group (x4)

    // staging assignment
    const int ar = tid >> 2;                // A row within tile
    const int ak = (tid & 3) * 4;           // A k-offset (float4)
    const int wk = tid >> 4;                // W k within chunk
    const int wc = (tid & 15) * 4;          // W col-offset (float4)

    float acc[4][4] = {};

    for (int k0 = 0; k0 < K; k0 += 16) {
        float4 av = *reinterpret_cast<const float4*>(&A[(size_t)(row0 + ar) * K + k0 + ak]);
        float4 wv = *reinterpret_cast<const float4*>(&W[(size_t)(k0 + wk) * 256 + col0 + wc]);
        __syncthreads();   // previous-iter LDS reads done before overwrite
        At[ak + 0][ar] = av.x;
        At[ak + 1][ar] = av.y;
        At[ak + 2][ar] = av.z;
        At[ak + 3][ar] = av.w;
        *reinterpret_cast<float4*>(&Wt[wk][wc]) = wv;
        __syncthreads();

        #pragma unroll
        for (int kk = 0; kk < 16; ++kk) {
            float4 a4 = *reinterpret_cast<const float4*>(&At[kk][tr * 4]);
            float4 b4 = *reinterpret_cast<const float4*>(&Wt[kk][tc * 4]);
            const float* ap = reinterpret_cast<const float*>(&a4);
            const float* bp = reinterpret_cast<const float*>(&b4);
            #pragma unroll
            for (int i = 0; i < 4; ++i)
                #pragma unroll
                for (int j = 0; j < 4; ++j)
                    acc[i][j] = fmaf(ap[i], bp[j], acc[i][j]);
        }
    }

    // fused bias + BN + relu epilogue
    #pragma unroll
    for (int j = 0; j < 4; ++j) {
        const int c = col0 + tc * 4 + j;
        const float s  = g[c] * rsqrtf(v[c] + BN_EPS);
        const float tt = be[c] - m[c] * s;
        const float bb = bias[c];
        #pragma unroll
        for (int i = 0; i < 4; ++i) {
            const float val = fmaf(acc[i][j] + bb, s, tt);
            out[(size_t)(row0 + tr * 4 + i) * 256 + c] = fmaxf(val, 0.f);
        }
    }
}

// ---------------- K3: partial max-pool over nodes ----------------
__global__ __launch_bounds__(256) void pool_kernel(const float* __restrict__ h,
                                                   float* __restrict__ part) {
    const int b  = blockIdx.x;
    const int nb = blockIdx.y;              // 8 node chunks of 128
    const int t  = threadIdx.x;             // feature col
    const float* hb = h + ((size_t)b * 1024 + (size_t)nb * 128) * 256;
    float mx = -3.4e38f;
    for (int n = 0; n < 128; ++n) mx = fmaxf(mx, hb[(size_t)n * 256 + t]);
    part[((size_t)b * 8 + nb) * 256 + t] = mx;
}

// ---------------- K4: final max + head Dense(3) ----------------
__global__ __launch_bounds__(256) void head_kernel(const float* __restrict__ part,
                                                   const float* __restrict__ wd,
                                                   const float* __restrict__ bd,
                                                   float* __restrict__ out) {
    const int b = blockIdx.x;
    const int t = threadIdx.x;
    __shared__ float pooled[256];
    float mx = part[((size_t)b * 8 + 0) * 256 + t];
    for (int nb = 1; nb < 8; ++nb)
        mx = fmaxf(mx, part[((size_t)b * 8 + nb) * 256 + t]);
    pooled[t] = mx;
    __syncthreads();
    if (t < 3) {
        float s = bd[t];
        for (int k = 0; k < 256; ++k) s = fmaf(pooled[k], wd[k * 3 + t], s);
        out[b * 3 + t] = s;
    }
}

extern "C" void kernel_launch(void* const* d_in, const int* in_sizes, int n_in,
                              void* d_out, int out_size, void* d_ws, size_t ws_size,
                              hipStream_t stream) {
    const float* x   = (const float*)d_in[0];
    const float* a   = (const float*)d_in[1];
    const float* eps = (const float*)d_in[2];
    const float* w1  = (const float*)d_in[3];
    const float* b1  = (const float*)d_in[4];
    const float* g1  = (const float*)d_in[5];
    const float* be1 = (const float*)d_in[6];
    const float* m1  = (const float*)d_in[7];
    const float* v1  = (const float*)d_in[8];
    const float* w2  = (const float*)d_in[9];
    const float* b2  = (const float*)d_in[10];
    const float* g2  = (const float*)d_in[11];
    const float* be2 = (const float*)d_in[12];
    const float* m2  = (const float*)d_in[13];
    const float* v2  = (const float*)d_in[14];
    const float* w3  = (const float*)d_in[15];
    const float* b3  = (const float*)d_in[16];
    const float* g3  = (const float*)d_in[17];
    const float* be3 = (const float*)d_in[18];
    const float* m3  = (const float*)d_in[19];
    const float* v3  = (const float*)d_in[20];
    const float* wd  = (const float*)d_in[21];
    const float* bd  = (const float*)d_in[22];
    float* out = (float*)d_out;

    // Workspace layout (peak 64.25 MB):
    //   h1 [32768][256] at  0 MB (32 MB)
    //   h0 [32768][128] at 32 MB (16 MB)  -- dead after mlp1
    //   h2 [32768][256] at 32 MB..64 MB (overlaps dead h0 + 16 MB more)
    //   part             at 64 MB (256 KB)
    char* ws = (char*)d_ws;
    float* h1   = (float*)(ws);
    float* h0   = (float*)(ws + (32u << 20));
    float* h2   = (float*)(ws + (32u << 20));   // overlays h0 (h0 dead by then)
    float* h3   = h1;                           // reuse (h1 dead after h2)
    float* part = (float*)(ws + (64u << 20));

    agg_kernel<<<32 * 1024, 128, 0, stream>>>(x, a, eps, h0);
    mlp_kernel<128><<<2048, 256, 0, stream>>>(h0, w1, b1, g1, be1, m1, v1, h1);
    mlp_kernel<256><<<2048, 256, 0, stream>>>(h1, w2, b2, g2, be2, m2, v2, h2);
    mlp_kernel<256><<<2048, 256, 0, stream>>>(h2, w3, b3, g3, be3, m3, v3, h3);
    pool_kernel<<<dim3(32, 8), 256, 0, stream>>>(h3, part);
    head_kernel<<<32, 256, 0, stream>>>(part, wd, bd, out);
}

// Round 3
// 320.802 us; speedup vs baseline: 1.3368x; 1.3368x over previous
//
#include <hip/hip_runtime.h>

#define BN_EPS 1e-3f

typedef __attribute__((ext_vector_type(8))) short bf16x8;
typedef __attribute__((ext_vector_type(4))) short short4v;
typedef __attribute__((ext_vector_type(4))) float f32x4;

__device__ __forceinline__ short f2bf(float f) {
    union { float f; unsigned u; } a; a.f = f;
    unsigned r = a.u + 0x7fffu + ((a.u >> 16) & 1u);
    return (short)(r >> 16);
}
__device__ __forceinline__ float bf2f(short s) {
    union { unsigned u; float f; } a;
    a.u = ((unsigned)(unsigned short)s) << 16;
    return a.f;
}

// ---------------- K1: sparse GIN aggregation (unchanged, known-correct) ----
__global__ __launch_bounds__(128) void agg_kernel(
    const float* __restrict__ x, const float* __restrict__ a,
    const float* __restrict__ epsp, float* __restrict__ h0) {
    const int row = blockIdx.x;            // b*1024 + i
    const int b   = row >> 10;
    const int t   = threadIdx.x;           // 0..127

    __shared__ int idx[1024];
    __shared__ int cnt;
    if (t == 0) cnt = 0;
    __syncthreads();

    const float4* arow = reinterpret_cast<const float4*>(a + (size_t)row * 1024);
    float4 v0 = arow[t];          // j = 4t .. 4t+3
    float4 v1 = arow[t + 128];    // j = 512 + 4t ..
    const int j0 = t * 4;
    if (v0.x != 0.f) idx[atomicAdd(&cnt, 1)] = j0 + 0;
    if (v0.y != 0.f) idx[atomicAdd(&cnt, 1)] = j0 + 1;
    if (v0.z != 0.f) idx[atomicAdd(&cnt, 1)] = j0 + 2;
    if (v0.w != 0.f) idx[atomicAdd(&cnt, 1)] = j0 + 3;
    if (v1.x != 0.f) idx[atomicAdd(&cnt, 1)] = 512 + j0 + 0;
    if (v1.y != 0.f) idx[atomicAdd(&cnt, 1)] = 512 + j0 + 1;
    if (v1.z != 0.f) idx[atomicAdd(&cnt, 1)] = 512 + j0 + 2;
    if (v1.w != 0.f) idx[atomicAdd(&cnt, 1)] = 512 + j0 + 3;
    __syncthreads();

    const int n = cnt;
    const float* xb = x + (size_t)b * (1024 * 128);
    float acc = (1.0f + epsp[0]) * xb[(size_t)(row & 1023) * 128 + t];
    for (int q = 0; q < n; ++q) {
        acc += xb[(size_t)idx[q] * 128 + t];
    }
    h0[(size_t)row * 128 + t] = acc;
}

// ---------------- K2: fused Dense+BN+ReLU via split-bf16 MFMA ----------------
// out = relu( (A@W + bias - m) * g/sqrt(v+eps) + be )
// BM=128, BN=128, BK=32; 4 waves (2x2), 64x64 per wave as 4x4 16x16 frags.
// fp32 inputs split into bf16 hi/lo; 3-term MFMA (hh + hl + lh).
template <int K, bool FUSE_POOL>
__global__ __launch_bounds__(256, 2) void mlp_mfma(
    const float* __restrict__ A, const float* __restrict__ W,
    const float* __restrict__ bias, const float* __restrict__ g,
    const float* __restrict__ be, const float* __restrict__ m,
    const float* __restrict__ v, float* __restrict__ out,
    float* __restrict__ pool) {
    // k-grouped LDS: [kg][row/col][8] -> ds_read_b128 contiguous per 16-lane grp
    __shared__ __align__(16) short Ah[4][128][8];
    __shared__ __align__(16) short Al[4][128][8];
    __shared__ __align__(16) short Bh[4][128][8];
    __shared__ __align__(16) short Bl[4][128][8];

    const int tid  = threadIdx.x;
    const int lane = tid & 63;
    const int wid  = tid >> 6;
    const int wm = wid >> 1, wn = wid & 1;
    const int row0 = blockIdx.x * 128;
    const int col0 = blockIdx.y * 128;
    const int lr = lane & 15;
    const int kg = lane >> 4;

    // staging assignments
    const int a_q   = tid & 7;        // k-quad within 32
    const int a_r   = tid >> 3;       // row base (stride 32)
    const int a_kg  = a_q >> 1;
    const int a_e0  = (a_q & 1) * 4;
    const int b_c   = tid & 127;      // col within tile
    const int b_kg0 = tid >> 7;       // 0/1

    f32x4 acc[4][4] = {};

    for (int k0 = 0; k0 < K; k0 += 32) {
        // issue global loads before the barrier (overlap prior MFMA)
        f32x4 av[4];
        #pragma unroll
        for (int p = 0; p < 4; ++p)
            av[p] = *reinterpret_cast<const f32x4*>(
                &A[(size_t)(row0 + p * 32 + a_r) * K + k0 + a_q * 4]);
        float wv[2][8];
        #pragma unroll
        for (int q = 0; q < 2; ++q) {
            const int kk = k0 + (b_kg0 + 2 * q) * 8;
            #pragma unroll
            for (int e = 0; e < 8; ++e)
                wv[q][e] = W[(size_t)(kk + e) * 256 + col0 + b_c];
        }
        __syncthreads();   // prior iteration's frag reads done
        #pragma unroll
        for (int p = 0; p < 4; ++p) {
            const int rr = p * 32 + a_r;
            float fx[4] = {av[p].x, av[p].y, av[p].z, av[p].w};
            short4v h4, l4;
            #pragma unroll
            for (int e = 0; e < 4; ++e) {
                const short hh = f2bf(fx[e]);
                h4[e] = hh;
                l4[e] = f2bf(fx[e] - bf2f(hh));
            }
            *reinterpret_cast<short4v*>(&Ah[a_kg][rr][a_e0]) = h4;
            *reinterpret_cast<short4v*>(&Al[a_kg][rr][a_e0]) = l4;
        }
        #pragma unroll
        for (int q = 0; q < 2; ++q) {
            bf16x8 h8, l8;
            #pragma unroll
            for (int e = 0; e < 8; ++e) {
                const short hh = f2bf(wv[q][e]);
                h8[e] = hh;
                l8[e] = f2bf(wv[q][e] - bf2f(hh));
            }
            *reinterpret_cast<bf16x8*>(&Bh[b_kg0 + 2 * q][b_c][0]) = h8;
            *reinterpret_cast<bf16x8*>(&Bl[b_kg0 + 2 * q][b_c][0]) = l8;
        }
        __syncthreads();

        bf16x8 ah[4], al[4];
        #pragma unroll
        for (int mi = 0; mi < 4; ++mi) {
            ah[mi] = *reinterpret_cast<const bf16x8*>(&Ah[kg][wm * 64 + mi * 16 + lr][0]);
            al[mi] = *reinterpret_cast<const bf16x8*>(&Al[kg][wm * 64 + mi * 16 + lr][0]);
        }
        #pragma unroll
        for (int ni = 0; ni < 4; ++ni) {
            bf16x8 bh = *reinterpret_cast<const bf16x8*>(&Bh[kg][wn * 64 + ni * 16 + lr][0]);
            bf16x8 bl = *reinterpret_cast<const bf16x8*>(&Bl[kg][wn * 64 + ni * 16 + lr][0]);
            #pragma unroll
            for (int mi = 0; mi < 4; ++mi) {
                acc[mi][ni] = __builtin_amdgcn_mfma_f32_16x16x32_bf16(ah[mi], bh, acc[mi][ni], 0, 0, 0);
                acc[mi][ni] = __builtin_amdgcn_mfma_f32_16x16x32_bf16(ah[mi], bl, acc[mi][ni], 0, 0, 0);
                acc[mi][ni] = __builtin_amdgcn_mfma_f32_16x16x32_bf16(al[mi], bh, acc[mi][ni], 0, 0, 0);
            }
        }
    }

    // epilogue: bias + BN + relu (+ optional fused max-pool)
    const int b = row0 >> 10;
    #pragma unroll
    for (int ni = 0; ni < 4; ++ni) {
        const int c = col0 + wn * 64 + ni * 16 + lr;
        const float s  = g[c] * rsqrtf(v[c] + BN_EPS);
        const float tt = be[c] - m[c] * s;
        const float bb = bias[c];
        if (FUSE_POOL) {
            float mx = 0.0f;    // relu floor
            #pragma unroll
            for (int mi = 0; mi < 4; ++mi)
                #pragma unroll
                for (int r = 0; r < 4; ++r)
                    mx = fmaxf(mx, fmaf(acc[mi][ni][r] + bb, s, tt));
            mx = fmaxf(mx, __shfl_xor(mx, 16));
            mx = fmaxf(mx, __shfl_xor(mx, 32));
            if (lane < 16)
                atomicMax((int*)&pool[b * 256 + c], __float_as_int(mx));
        } else {
            #pragma unroll
            for (int mi = 0; mi < 4; ++mi) {
                const int rbase = row0 + wm * 64 + mi * 16 + (lane >> 4) * 4;
                #pragma unroll
                for (int r = 0; r < 4; ++r) {
                    const float val = fmaf(acc[mi][ni][r] + bb, s, tt);
                    out[(size_t)(rbase + r) * 256 + c] = fmaxf(val, 0.f);
                }
            }
        }
    }
}

// ---------------- K3: pool init (relu floor = 0) ----------------
__global__ __launch_bounds__(256) void pool_init(float* __restrict__ pool) {
    pool[blockIdx.x * 256 + threadIdx.x] = 0.0f;
}

// ---------------- K4: head Dense(3), wave-parallel ----------------
__global__ __launch_bounds__(256) void head_kernel(const float* __restrict__ pool,
                                                   const float* __restrict__ wd,
                                                   const float* __restrict__ bd,
                                                   float* __restrict__ out) {
    const int b = blockIdx.x;
    const int t = threadIdx.x;
    const int w = t >> 6;          // wave id; waves 0..2 -> outputs 0..2
    const int lane = t & 63;
    if (w < 3) {
        float s = 0.f;
        #pragma unroll
        for (int k = 0; k < 256; k += 64)
            s += pool[b * 256 + k + lane] * wd[(k + lane) * 3 + w];
        #pragma unroll
        for (int off = 32; off; off >>= 1) s += __shfl_down(s, off);
        if (lane == 0) out[b * 3 + w] = s + bd[w];
    }
}

extern "C" void kernel_launch(void* const* d_in, const int* in_sizes, int n_in,
                              void* d_out, int out_size, void* d_ws, size_t ws_size,
                              hipStream_t stream) {
    const float* x   = (const float*)d_in[0];
    const float* a   = (const float*)d_in[1];
    const float* eps = (const float*)d_in[2];
    const float* w1  = (const float*)d_in[3];
    const float* b1  = (const float*)d_in[4];
    const float* g1  = (const float*)d_in[5];
    const float* be1 = (const float*)d_in[6];
    const float* m1  = (const float*)d_in[7];
    const float* v1  = (const float*)d_in[8];
    const float* w2  = (const float*)d_in[9];
    const float* b2  = (const float*)d_in[10];
    const float* g2  = (const float*)d_in[11];
    const float* be2 = (const float*)d_in[12];
    const float* m2  = (const float*)d_in[13];
    const float* v2  = (const float*)d_in[14];
    const float* w3  = (const float*)d_in[15];
    const float* b3  = (const float*)d_in[16];
    const float* g3  = (const float*)d_in[17];
    const float* be3 = (const float*)d_in[18];
    const float* m3  = (const float*)d_in[19];
    const float* v3  = (const float*)d_in[20];
    const float* wd  = (const float*)d_in[21];
    const float* bd  = (const float*)d_in[22];
    float* out = (float*)d_out;

    // Workspace: h0 @0 (16MB), h1 @16M (32MB), h2 @48M (32MB), pool @80M (32KB)
    char* ws = (char*)d_ws;
    float* h0   = (float*)(ws);
    float* h1   = (float*)(ws + (16u << 20));
    float* h2   = (float*)(ws + (48u << 20));
    float* pool = (float*)(ws + (80u << 20));

    pool_init<<<32, 256, 0, stream>>>(pool);
    agg_kernel<<<32 * 1024, 128, 0, stream>>>(x, a, eps, h0);
    mlp_mfma<128, false><<<dim3(256, 2), 256, 0, stream>>>(h0, w1, b1, g1, be1, m1, v1, h1, nullptr);
    mlp_mfma<256, false><<<dim3(256, 2), 256, 0, stream>>>(h1, w2, b2, g2, be2, m2, v2, h2, nullptr);
    mlp_mfma<256, true ><<<dim3(256, 2), 256, 0, stream>>>(h2, w3, b3, g3, be3, m3, v3, nullptr, pool);
    head_kernel<<<32, 256, 0, stream>>>(pool, wd, bd, out);
}

// Round 4
// 294.840 us; speedup vs baseline: 1.4545x; 1.0881x over previous
//
#include <hip/hip_runtime.h>

#define BN_EPS 1e-3f

typedef __attribute__((ext_vector_type(8))) short bf16x8;
typedef __attribute__((ext_vector_type(4))) float f32x4;

__device__ __forceinline__ short f2bf(float f) {
    union { float f; unsigned u; } a; a.f = f;
    unsigned r = a.u + 0x7fffu + ((a.u >> 16) & 1u);
    return (short)(r >> 16);
}
__device__ __forceinline__ float bf2f(short s) {
    union { unsigned u; float f; } a;
    a.u = ((unsigned)(unsigned short)s) << 16;
    return a.f;
}

// ---------------- K1: sparse GIN aggregation (unchanged, verified) ----------
__global__ __launch_bounds__(128) void agg_kernel(
    const float* __restrict__ x, const float* __restrict__ a,
    const float* __restrict__ epsp, float* __restrict__ h0) {
    const int row = blockIdx.x;            // b*1024 + i
    const int b   = row >> 10;
    const int t   = threadIdx.x;           // 0..127

    __shared__ int idx[1024];
    __shared__ int cnt;
    if (t == 0) cnt = 0;
    __syncthreads();

    const float4* arow = reinterpret_cast<const float4*>(a + (size_t)row * 1024);
    float4 v0 = arow[t];
    float4 v1 = arow[t + 128];
    const int j0 = t * 4;
    if (v0.x != 0.f) idx[atomicAdd(&cnt, 1)] = j0 + 0;
    if (v0.y != 0.f) idx[atomicAdd(&cnt, 1)] = j0 + 1;
    if (v0.z != 0.f) idx[atomicAdd(&cnt, 1)] = j0 + 2;
    if (v0.w != 0.f) idx[atomicAdd(&cnt, 1)] = j0 + 3;
    if (v1.x != 0.f) idx[atomicAdd(&cnt, 1)] = 512 + j0 + 0;
    if (v1.y != 0.f) idx[atomicAdd(&cnt, 1)] = 512 + j0 + 1;
    if (v1.z != 0.f) idx[atomicAdd(&cnt, 1)] = 512 + j0 + 2;
    if (v1.w != 0.f) idx[atomicAdd(&cnt, 1)] = 512 + j0 + 3;
    __syncthreads();

    const int n = cnt;
    const float* xb = x + (size_t)b * (1024 * 128);
    float acc = (1.0f + epsp[0]) * xb[(size_t)(row & 1023) * 128 + t];
    for (int q = 0; q < n; ++q) {
        acc += xb[(size_t)idx[q] * 128 + t];
    }
    h0[(size_t)row * 128 + t] = acc;
}

// ---------------- K2: W pre-split into LDS chunk images ----------------
// Layout per 32-k chunk (16384 ushorts = 32KB): hi[4 kg][256 c][8 e] then lo.
// Layer bases (ushorts): L1=0 (4 chunks), L2=65536 (8), L3=196608 (8).
__global__ __launch_bounds__(256) void prep_w(
    const float* __restrict__ w1, const float* __restrict__ w2,
    const float* __restrict__ w3, ushort* __restrict__ Wp) {
    const int k = blockIdx.x;      // 0..639 global k row
    const int c = threadIdx.x;     // 0..255
    const float* src; int kl, base;
    if (k < 128)      { src = w1; kl = k;       base = 0; }
    else if (k < 384) { src = w2; kl = k - 128; base = 65536; }
    else              { src = w3; kl = k - 384; base = 196608; }
    const float val = src[(size_t)kl * 256 + c];
    const short hi = f2bf(val);
    const short lo = f2bf(val - bf2f(hi));
    const int off = base + (kl >> 5) * 16384 + ((((kl >> 3) & 3) * 256 + c) * 8) + (kl & 7);
    Wp[off]        = (ushort)hi;
    Wp[off + 8192] = (ushort)lo;
}

// ---------------- K3: fused 3-layer MLP + max-pool ----------------
// 256 blocks x 512 thr (8 waves: 4 row-groups x 2 col-groups).
// Block owns 128 rows; wave tile 32 rows x 128 cols = acc[2][8] f32x4.
// All intermediates stay in registers; per-chunk hi/lo redistribution
// through a 16KB LDS A-buffer; W staged from pre-split chunk images.
__global__ __launch_bounds__(512, 2) void fused_mlp(
    const float* __restrict__ h0, const ushort* __restrict__ Wp,
    const float* __restrict__ b1, const float* __restrict__ g1,
    const float* __restrict__ be1, const float* __restrict__ m1,
    const float* __restrict__ v1,
    const float* __restrict__ b2, const float* __restrict__ g2,
    const float* __restrict__ be2, const float* __restrict__ m2,
    const float* __restrict__ v2,
    const float* __restrict__ b3, const float* __restrict__ g3,
    const float* __restrict__ be3, const float* __restrict__ m3,
    const float* __restrict__ v3,
    float* __restrict__ pool) {
    __shared__ __align__(16) ushort Wb[2][4][256][8];    // 32KB: [hi/lo][kg][col][e]
    __shared__ __align__(16) ushort Ab[2][4][4][32][8];  // 16KB: [hi/lo][wr][kg][row][e]

    const int tid  = threadIdx.x;
    const int lane = tid & 63;
    const int wid  = tid >> 6;
    const int wr   = wid >> 1;     // row group (32 rows each)
    const int wn   = wid & 1;      // col group (128 cols each)
    const int lr   = lane & 15;
    const int kg   = lane >> 4;
    const int row0 = blockIdx.x * 128;

    f32x4 acc1[2][8] = {};
    f32x4 acc2[2][8] = {};

    // ---- Layer 1: A from global h0 (fp32), K=128, 4 chunks ----
    const int arow = tid >> 2;          // 0..127
    const int akq  = tid & 3;           // k-quad (8 floats)
    const float* aptr = h0 + (size_t)(row0 + arow) * 128 + akq * 8;

    #pragma unroll
    for (int kc = 0; kc < 4; ++kc) {
        f32x4 a0 = *reinterpret_cast<const f32x4*>(aptr + kc * 32);
        f32x4 a1 = *reinterpret_cast<const f32x4*>(aptr + kc * 32 + 4);
        const f32x4* wsrc = reinterpret_cast<const f32x4*>(Wp + kc * 16384);
        f32x4 wv0 = wsrc[tid], wv1 = wsrc[512 + tid];
        f32x4 wv2 = wsrc[1024 + tid], wv3 = wsrc[1536 + tid];
        __syncthreads();                 // prior chunk's frag reads done
        {
            float av[8] = {a0.x, a0.y, a0.z, a0.w, a1.x, a1.y, a1.z, a1.w};
            bf16x8 hi, lo;
            #pragma unroll
            for (int e = 0; e < 8; ++e) {
                const short h = f2bf(av[e]);
                hi[e] = h; lo[e] = f2bf(av[e] - bf2f(h));
            }
            *reinterpret_cast<bf16x8*>(&Ab[0][arow >> 5][akq][arow & 31][0]) = hi;
            *reinterpret_cast<bf16x8*>(&Ab[1][arow >> 5][akq][arow & 31][0]) = lo;
        }
        f32x4* wdst = reinterpret_cast<f32x4*>(Wb);
        wdst[tid] = wv0; wdst[512 + tid] = wv1;
        wdst[1024 + tid] = wv2; wdst[1536 + tid] = wv3;
        __syncthreads();

        bf16x8 ah0 = *reinterpret_cast<bf16x8*>(&Ab[0][wr][kg][lr][0]);
        bf16x8 al0 = *reinterpret_cast<bf16x8*>(&Ab[1][wr][kg][lr][0]);
        bf16x8 ah1 = *reinterpret_cast<bf16x8*>(&Ab[0][wr][kg][16 + lr][0]);
        bf16x8 al1 = *reinterpret_cast<bf16x8*>(&Ab[1][wr][kg][16 + lr][0]);
        #pragma unroll
        for (int ni = 0; ni < 8; ++ni) {
            bf16x8 bh = *reinterpret_cast<bf16x8*>(&Wb[0][kg][wn * 128 + ni * 16 + lr][0]);
            bf16x8 bl = *reinterpret_cast<bf16x8*>(&Wb[1][kg][wn * 128 + ni * 16 + lr][0]);
            acc1[0][ni] = __builtin_amdgcn_mfma_f32_16x16x32_bf16(ah0, bh, acc1[0][ni], 0, 0, 0);
            acc1[0][ni] = __builtin_amdgcn_mfma_f32_16x16x32_bf16(ah0, bl, acc1[0][ni], 0, 0, 0);
            acc1[0][ni] = __builtin_amdgcn_mfma_f32_16x16x32_bf16(al0, bh, acc1[0][ni], 0, 0, 0);
            acc1[1][ni] = __builtin_amdgcn_mfma_f32_16x16x32_bf16(ah1, bh, acc1[1][ni], 0, 0, 0);
            acc1[1][ni] = __builtin_amdgcn_mfma_f32_16x16x32_bf16(ah1, bl, acc1[1][ni], 0, 0, 0);
            acc1[1][ni] = __builtin_amdgcn_mfma_f32_16x16x32_bf16(al1, bh, acc1[1][ni], 0, 0, 0);
        }
    }

    // epilogue 1: bias+BN+relu in place
    #pragma unroll
    for (int ni = 0; ni < 8; ++ni) {
        const int c = wn * 128 + ni * 16 + lr;
        const float s  = g1[c] * rsqrtf(v1[c] + BN_EPS);
        const float tt = be1[c] - m1[c] * s;
        const float bb = b1[c];
        #pragma unroll
        for (int mi = 0; mi < 2; ++mi)
            #pragma unroll
            for (int r = 0; r < 4; ++r)
                acc1[mi][ni][r] = fmaxf(fmaf(acc1[mi][ni][r] + bb, s, tt), 0.f);
    }

    // ---- Layer 2: A from acc1 (regs), K=256, 8 chunks ----
    #pragma unroll
    for (int kc = 0; kc < 8; ++kc) {
        const f32x4* wsrc = reinterpret_cast<const f32x4*>(Wp + 65536 + kc * 16384);
        f32x4 wv0 = wsrc[tid], wv1 = wsrc[512 + tid];
        f32x4 wv2 = wsrc[1024 + tid], wv3 = wsrc[1536 + tid];
        __syncthreads();
        if (wn == (kc >> 2)) {           // this wave's cols cover chunk kc
            #pragma unroll
            for (int j = 0; j < 2; ++j) {
                const int ni  = (kc & 3) * 2 + j;
                const int kgw = j * 2 + (lr >> 3);
                const int e   = lr & 7;
                #pragma unroll
                for (int mi = 0; mi < 2; ++mi)
                    #pragma unroll
                    for (int r = 0; r < 4; ++r) {
                        const float val = acc1[mi][ni][r];
                        const short h = f2bf(val);
                        Ab[0][wr][kgw][mi * 16 + kg * 4 + r][e] = (ushort)h;
                        Ab[1][wr][kgw][mi * 16 + kg * 4 + r][e] = (ushort)f2bf(val - bf2f(h));
                    }
            }
        }
        f32x4* wdst = reinterpret_cast<f32x4*>(Wb);
        wdst[tid] = wv0; wdst[512 + tid] = wv1;
        wdst[1024 + tid] = wv2; wdst[1536 + tid] = wv3;
        __syncthreads();

        bf16x8 ah0 = *reinterpret_cast<bf16x8*>(&Ab[0][wr][kg][lr][0]);
        bf16x8 al0 = *reinterpret_cast<bf16x8*>(&Ab[1][wr][kg][lr][0]);
        bf16x8 ah1 = *reinterpret_cast<bf16x8*>(&Ab[0][wr][kg][16 + lr][0]);
        bf16x8 al1 = *reinterpret_cast<bf16x8*>(&Ab[1][wr][kg][16 + lr][0]);
        #pragma unroll
        for (int ni = 0; ni < 8; ++ni) {
            bf16x8 bh = *reinterpret_cast<bf16x8*>(&Wb[0][kg][wn * 128 + ni * 16 + lr][0]);
            bf16x8 bl = *reinterpret_cast<bf16x8*>(&Wb[1][kg][wn * 128 + ni * 16 + lr][0]);
            acc2[0][ni] = __builtin_amdgcn_mfma_f32_16x16x32_bf16(ah0, bh, acc2[0][ni], 0, 0, 0);
            acc2[0][ni] = __builtin_amdgcn_mfma_f32_16x16x32_bf16(ah0, bl, acc2[0][ni], 0, 0, 0);
            acc2[0][ni] = __builtin_amdgcn_mfma_f32_16x16x32_bf16(al0, bh, acc2[0][ni], 0, 0, 0);
            acc2[1][ni] = __builtin_amdgcn_mfma_f32_16x16x32_bf16(ah1, bh, acc2[1][ni], 0, 0, 0);
            acc2[1][ni] = __builtin_amdgcn_mfma_f32_16x16x32_bf16(ah1, bl, acc2[1][ni], 0, 0, 0);
            acc2[1][ni] = __builtin_amdgcn_mfma_f32_16x16x32_bf16(al1, bh, acc2[1][ni], 0, 0, 0);
        }
    }

    // epilogue 2
    #pragma unroll
    for (int ni = 0; ni < 8; ++ni) {
        const int c = wn * 128 + ni * 16 + lr;
        const float s  = g2[c] * rsqrtf(v2[c] + BN_EPS);
        const float tt = be2[c] - m2[c] * s;
        const float bb = b2[c];
        #pragma unroll
        for (int mi = 0; mi < 2; ++mi)
            #pragma unroll
            for (int r = 0; r < 4; ++r)
                acc2[mi][ni][r] = fmaxf(fmaf(acc2[mi][ni][r] + bb, s, tt), 0.f);
    }

    // ---- Layer 3: A from acc2, accumulate into re-zeroed acc1 ----
    #pragma unroll
    for (int mi = 0; mi < 2; ++mi)
        #pragma unroll
        for (int ni = 0; ni < 8; ++ni)
            #pragma unroll
            for (int r = 0; r < 4; ++r)
                acc1[mi][ni][r] = 0.f;

    #pragma unroll
    for (int kc = 0; kc < 8; ++kc) {
        const f32x4* wsrc = reinterpret_cast<const f32x4*>(Wp + 196608 + kc * 16384);
        f32x4 wv0 = wsrc[tid], wv1 = wsrc[512 + tid];
        f32x4 wv2 = wsrc[1024 + tid], wv3 = wsrc[1536 + tid];
        __syncthreads();
        if (wn == (kc >> 2)) {
            #pragma unroll
            for (int j = 0; j < 2; ++j) {
                const int ni  = (kc & 3) * 2 + j;
                const int kgw = j * 2 + (lr >> 3);
                const int e   = lr & 7;
                #pragma unroll
                for (int mi = 0; mi < 2; ++mi)
                    #pragma unroll
                    for (int r = 0; r < 4; ++r) {
                        const float val = acc2[mi][ni][r];
                        const short h = f2bf(val);
                        Ab[0][wr][kgw][mi * 16 + kg * 4 + r][e] = (ushort)h;
                        Ab[1][wr][kgw][mi * 16 + kg * 4 + r][e] = (ushort)f2bf(val - bf2f(h));
                    }
            }
        }
        f32x4* wdst = reinterpret_cast<f32x4*>(Wb);
        wdst[tid] = wv0; wdst[512 + tid] = wv1;
        wdst[1024 + tid] = wv2; wdst[1536 + tid] = wv3;
        __syncthreads();

        bf16x8 ah0 = *reinterpret_cast<bf16x8*>(&Ab[0][wr][kg][lr][0]);
        bf16x8 al0 = *reinterpret_cast<bf16x8*>(&Ab[1][wr][kg][lr][0]);
        bf16x8 ah1 = *reinterpret_cast<bf16x8*>(&Ab[0][wr][kg][16 + lr][0]);
        bf16x8 al1 = *reinterpret_cast<bf16x8*>(&Ab[1][wr][kg][16 + lr][0]);
        #pragma unroll
        for (int ni = 0; ni < 8; ++ni) {
            bf16x8 bh = *reinterpret_cast<bf16x8*>(&Wb[0][kg][wn * 128 + ni * 16 + lr][0]);
            bf16x8 bl = *reinterpret_cast<bf16x8*>(&Wb[1][kg][wn * 128 + ni * 16 + lr][0]);
            acc1[0][ni] = __builtin_amdgcn_mfma_f32_16x16x32_bf16(ah0, bh, acc1[0][ni], 0, 0, 0);
            acc1[0][ni] = __builtin_amdgcn_mfma_f32_16x16x32_bf16(ah0, bl, acc1[0][ni], 0, 0, 0);
            acc1[0][ni] = __builtin_amdgcn_mfma_f32_16x16x32_bf16(al0, bh, acc1[0][ni], 0, 0, 0);
            acc1[1][ni] = __builtin_amdgcn_mfma_f32_16x16x32_bf16(ah1, bh, acc1[1][ni], 0, 0, 0);
            acc1[1][ni] = __builtin_amdgcn_mfma_f32_16x16x32_bf16(ah1, bl, acc1[1][ni], 0, 0, 0);
            acc1[1][ni] = __builtin_amdgcn_mfma_f32_16x16x32_bf16(al1, bh, acc1[1][ni], 0, 0, 0);
        }
    }

    // epilogue 3: bias+BN+relu -> wave max over 32 rows -> atomicMax pool
    const int b = blockIdx.x >> 3;
    #pragma unroll
    for (int ni = 0; ni < 8; ++ni) {
        const int c = wn * 128 + ni * 16 + lr;
        const float s  = g3[c] * rsqrtf(v3[c] + BN_EPS);
        const float tt = be3[c] - m3[c] * s;
        const float bb = b3[c];
        float mx = 0.0f;                 // relu floor
        #pragma unroll
        for (int mi = 0; mi < 2; ++mi)
            #pragma unroll
            for (int r = 0; r < 4; ++r)
                mx = fmaxf(mx, fmaf(acc1[mi][ni][r] + bb, s, tt));
        mx = fmaxf(mx, __shfl_xor(mx, 16));
        mx = fmaxf(mx, __shfl_xor(mx, 32));
        if (lane < 16)
            atomicMax((int*)&pool[b * 256 + c], __float_as_int(mx));
    }
}

// ---------------- K4: pool init (relu floor = 0) ----------------
__global__ __launch_bounds__(256) void pool_init(float* __restrict__ pool) {
    pool[blockIdx.x * 256 + threadIdx.x] = 0.0f;
}

// ---------------- K5: head Dense(3), wave-parallel ----------------
__global__ __launch_bounds__(256) void head_kernel(const float* __restrict__ pool,
                                                   const float* __restrict__ wd,
                                                   const float* __restrict__ bd,
                                                   float* __restrict__ out) {
    const int b = blockIdx.x;
    const int t = threadIdx.x;
    const int w = t >> 6;
    const int lane = t & 63;
    if (w < 3) {
        float s = 0.f;
        #pragma unroll
        for (int k = 0; k < 256; k += 64)
            s += pool[b * 256 + k + lane] * wd[(k + lane) * 3 + w];
        #pragma unroll
        for (int off = 32; off; off >>= 1) s += __shfl_down(s, off);
        if (lane == 0) out[b * 3 + w] = s + bd[w];
    }
}

extern "C" void kernel_launch(void* const* d_in, const int* in_sizes, int n_in,
                              void* d_out, int out_size, void* d_ws, size_t ws_size,
                              hipStream_t stream) {
    const float* x   = (const float*)d_in[0];
    const float* a   = (const float*)d_in[1];
    const float* eps = (const float*)d_in[2];
    const float* w1  = (const float*)d_in[3];
    const float* b1  = (const float*)d_in[4];
    const float* g1  = (const float*)d_in[5];
    const float* be1 = (const float*)d_in[6];
    const float* m1  = (const float*)d_in[7];
    const float* v1  = (const float*)d_in[8];
    const float* w2  = (const float*)d_in[9];
    const float* b2  = (const float*)d_in[10];
    const float* g2  = (const float*)d_in[11];
    const float* be2 = (const float*)d_in[12];
    const float* m2  = (const float*)d_in[13];
    const float* v2  = (const float*)d_in[14];
    const float* w3  = (const float*)d_in[15];
    const float* b3  = (const float*)d_in[16];
    const float* g3  = (const float*)d_in[17];
    const float* be3 = (const float*)d_in[18];
    const float* m3  = (const float*)d_in[19];
    const float* v3  = (const float*)d_in[20];
    const float* wd  = (const float*)d_in[21];
    const float* bd  = (const float*)d_in[22];
    float* out = (float*)d_out;

    // Workspace: h0 @0 (16MB), Wp @16MB (640KB), pool @17MB (32KB)
    char* ws = (char*)d_ws;
    float*  h0   = (float*)(ws);
    ushort* Wp   = (ushort*)(ws + (16u << 20));
    float*  pool = (float*)(ws + (17u << 20));

    pool_init<<<32, 256, 0, stream>>>(pool);
    prep_w<<<640, 256, 0, stream>>>(w1, w2, w3, Wp);
    agg_kernel<<<32 * 1024, 128, 0, stream>>>(x, a, eps, h0);
    fused_mlp<<<256, 512, 0, stream>>>(h0, Wp,
        b1, g1, be1, m1, v1,
        b2, g2, be2, m2, v2,
        b3, g3, be3, m3, v3, pool);
    head_kernel<<<32, 256, 0, stream>>>(pool, wd, bd, out);
}